// Round 2
// baseline (208.998 us; speedup 1.0000x reference)
//
#include <hip/hip_runtime.h>

// GGNN on MI355X. N=100000, E=1000000, H=M=64, C=16.
// R6: deterministic bucket sort (k_s1 histogram / k_s2 scan / k_s3 place /
//     k_g gather / k_mm MFMA GRU+head). ws layout unchanged.
// R7 post-mortem: launch_bounds(256,4) let the backend keep targeting max
// occupancy -> staged loads re-sunk, VGPR=60, still load->wait->MFMA
// lockstep. Per-wave latency ~63k cy vs ~5.6k cy issue: ~90 serialized
// cross-XCD loads (k_g writes bucket b on XCD b%8; k_mm block j reads on
// XCD j%8 != b%8 -> L2 miss).
// R8: (1) launch_bounds(256,2): 256-VGPR budget, scheduler stops re-sinking;
//     (2) asm "" :: "v"(frag) pins after each staged cluster -> one waitcnt
//     per 12-16 loads instead of per-load; (3) XCD-aligned block map
//     j -> (b=8*(j>>4)+(j&7), s=(j>>3)&1), n0=b*128+s*64: reader lands on
//     the XCD whose L2 holds s1b/s0b/cc (3.2MB/XCD < 4MB). Grid 1563->1568
//     (bijective; guarded). Math order identical to R6/R7 -> absmax must
//     stay 0.0078125 exactly.
// ws: [featb | region 782*1600 | hist 245*782 | blockBase 245*782 |
//      bucketCnt 782 | cc N | s1b | s0b | wb | flag]

typedef __bf16 bf16x8 __attribute__((ext_vector_type(8)));
typedef float  f32x4  __attribute__((ext_vector_type(4)));
typedef int    i32x4  __attribute__((ext_vector_type(4)));

#define MFMA16 __builtin_amdgcn_mfma_f32_16x16x32_bf16
#define NN   100000
#define EE   1000000
#define BB   782     // buckets (dst >> 7)
#define NPB  128     // nodes per bucket
#define ECAP 1600    // bucket region capacity (mean 1280, +9 sigma)
#define DCAP 48      // per-node degree cap (Poisson(10), P(>=48) ~ 1e-17)
#define CSTRD 49     // CSR LDS stride (conflict pad)
#define NB   245     // histogram blocks (4096 edges each)

__device__ __forceinline__ float sigmoidf_(float x) {
    return 1.0f / (1.0f + __expf(-x));
}

// pin: force the staged fragment to be materialized here (blocks the
// scheduler from re-sinking the load to its use; one waitcnt per cluster).
__device__ __forceinline__ void pin(bf16x8 x) { asm volatile("" :: "v"(x)); }

// ---- fused init: dtype detect / weight cvt / feature cvt ----
__global__ __launch_bounds__(256) void k_init(const unsigned char* __restrict__ et,
                                              const float* __restrict__ feat,
                                              const float* __restrict__ w0,
                                              const float* __restrict__ w1,
                                              const float* __restrict__ wih,
                                              const float* __restrict__ whh,
                                              const float* __restrict__ wout,
                                              __bf16* __restrict__ featb,
                                              __bf16* __restrict__ wb,
                                              int* __restrict__ flag) {
    int b = blockIdx.x, tid = threadIdx.x;
    if (b == 0) {
        // flag=1 iff any nonzero byte at offset%4!=0 in first 64KB (bool
        // storage); int32 0/1 storage has bytes 1..3 of every word zero.
        __shared__ int sdet[4];
        const i32x4* p = (const i32x4*)et + tid * 16;  // 256 B per thread
        unsigned acc = 0;
#pragma unroll
        for (int j = 0; j < 16; j++) {
            i32x4 w = p[j];
            acc |= (unsigned)(w[0] | w[1] | w[2] | w[3]) & 0xffffff00u;
        }
        unsigned long long m = __ballot(acc != 0);
        if ((tid & 63) == 0) sdet[tid >> 6] = (m != 0ULL);
        __syncthreads();
        if (tid == 0) *flag = sdet[0] | sdet[1] | sdet[2] | sdet[3];
        return;
    }
    if (b < 133) {  // 132 blocks * 256 = 33792 weights exactly
        int i = (b - 1) * 256 + tid;
        float v;
        if      (i < 4096)  v = w0[i];
        else if (i < 8192)  v = w1[i - 4096];
        else if (i < 20480) v = wih[i - 8192];
        else if (i < 32768) v = whh[i - 20480];
        else                v = wout[i - 32768];
        wb[i] = (__bf16)v;
        return;
    }
    long i = ((long)(b - 133) * 256 + tid) * 4;
    if (i >= (long)NN * 64) return;
    f32x4 v = *(const f32x4*)(feat + i);
    union { __bf16 e[4]; unsigned long long u; } o;
#pragma unroll
    for (int j = 0; j < 4; j++) o.e[j] = (__bf16)v[j];
    *(unsigned long long*)(featb + i) = o.u;
}

// ---- s1: per-block bucket histogram (LDS non-returning atomics only) ----
__global__ __launch_bounds__(512) void k_s1(const int* __restrict__ dst,
                                            int* __restrict__ hist) {
    __shared__ int cnt[BB];
    int blk = blockIdx.x, tid = threadIdx.x;
    for (int i = tid; i < BB; i += 512) cnt[i] = 0;
    __syncthreads();
    long e0 = (long)blk * 4096 + tid * 8;  // EE % 8 == 0: no scalar tail
    if (e0 < EE) {
        i32x4 d0 = *(const i32x4*)(dst + e0);
        i32x4 d1 = *(const i32x4*)(dst + e0 + 4);
#pragma unroll
        for (int j = 0; j < 4; j++) atomicAdd(&cnt[d0[j] >> 7], 1);
#pragma unroll
        for (int j = 0; j < 4; j++) atomicAdd(&cnt[d1[j] >> 7], 1);
    }
    __syncthreads();
    for (int i = tid; i < BB; i += 512) hist[blk * BB + i] = cnt[i];
}

// ---- s2: exclusive scan over blocks per bucket (1 wave/bucket) ----
__global__ __launch_bounds__(256) void k_s2(const int* __restrict__ hist,
                                            int* __restrict__ blockBase,
                                            int* __restrict__ bucketCnt) {
    int b = blockIdx.x * 4 + (threadIdx.x >> 6);
    int lane = threadIdx.x & 63;
    if (b >= BB) return;
    int carry = 0;
    for (int c = 0; c < 4; c++) {       // ceil(245/64) = 4 chunks
        int blk = c * 64 + lane;
        int v = (blk < NB) ? hist[blk * BB + b] : 0;
        int x = v;
#pragma unroll
        for (int off = 1; off < 64; off <<= 1) {
            int y = __shfl_up(x, off, 64);
            if (lane >= off) x += y;
        }
        if (blk < NB) blockBase[blk * BB + b] = x - v + carry;
        carry += __shfl(x, 63, 64);
    }
    if (lane == 0) bucketCnt[b] = carry;
}

// ---- s3: place edges deterministically (LDS cursors seeded w/ blockBase) ----
__global__ __launch_bounds__(512) void k_s3(const int* __restrict__ src,
                                            const int* __restrict__ dst,
                                            const unsigned char* __restrict__ etype,
                                            const int* __restrict__ flag,
                                            const int* __restrict__ blockBase,
                                            int* __restrict__ region) {
    __shared__ int cur[BB];
    int blk = blockIdx.x, tid = threadIdx.x;
    for (int i = tid; i < BB; i += 512) cur[i] = blockBase[blk * BB + i];
    __syncthreads();
    long e0 = (long)blk * 4096 + tid * 8;
    if (e0 >= EE) return;
    i32x4 s0 = *(const i32x4*)(src + e0);
    i32x4 s1 = *(const i32x4*)(src + e0 + 4);
    i32x4 d0 = *(const i32x4*)(dst + e0);
    i32x4 d1 = *(const i32x4*)(dst + e0 + 4);
    int t[8];
    if (*flag) {  // 1-byte bool storage
        unsigned long long w = *(const unsigned long long*)(etype + e0);
#pragma unroll
        for (int j = 0; j < 8; j++) t[j] = (int)((w >> (8 * j)) & 0xff);
    } else {      // int32 storage
        i32x4 w0 = *(const i32x4*)((const int*)etype + e0);
        i32x4 w1 = *(const i32x4*)((const int*)etype + e0 + 4);
#pragma unroll
        for (int j = 0; j < 4; j++) { t[j] = w0[j]; t[4 + j] = w1[j]; }
    }
    int dd[8] = {d0[0], d0[1], d0[2], d0[3], d1[0], d1[1], d1[2], d1[3]};
    int ss[8] = {s0[0], s0[1], s0[2], s0[3], s1[0], s1[1], s1[2], s1[3]};
#pragma unroll
    for (int j = 0; j < 8; j++) {
        int b  = dd[j] >> 7;
        int nl = dd[j] & 127;
        int r  = atomicAdd(&cur[b], 1);  // LDS returning atomic: fast
        if (r < ECAP)
            region[b * ECAP + r] = (nl << 18) | ((t[j] ? 1 : 0) << 17) | ss[j];
    }
}

// ---- gather: per-bucket CSR build in LDS, then 8 waves x 16 nodes ----
__global__ __launch_bounds__(512) void k_g(const __bf16* __restrict__ featb,
                                           const int* __restrict__ region,
                                           const int* __restrict__ bucketCnt,
                                           __bf16* __restrict__ s1b,
                                           __bf16* __restrict__ s0b,
                                           int* __restrict__ cc) {
    __shared__ int ncnt[NPB];
    __shared__ int csr[NPB * CSTRD];  // stride 49: breaks 2-bank aliasing
    int b = blockIdx.x, tid = threadIdx.x;
    int cntE = min(bucketCnt[b], ECAP);
    if (tid < NPB) ncnt[tid] = 0;
    __syncthreads();
    const int* reg = region + b * ECAP;
    for (int i = tid; i < cntE; i += 512) {
        int rec = reg[i];
        int nl = rec >> 18;
        int r = atomicAdd(&ncnt[nl], 1);
        if (r < DCAP) csr[nl * CSTRD + r] = rec & 0x3ffff;  // type|src
    }
    __syncthreads();

    int lane = tid & 63, wave = tid >> 6;
    int L = lane & 15, q = lane >> 4;
    int nl = wave * 16 + L;        // 8 waves x 16 nodes = 128
    int n = b * NPB + nl;
    int cnt = (n < NN) ? min(ncnt[nl], DCAP) : 0;
    const int* eb = &csr[nl * CSTRD];

    float sA[16], s1[16];
#pragma unroll
    for (int j = 0; j < 16; j++) { sA[j] = 0.f; s1[j] = 0.f; }
    int c1 = 0;
    int i = 0;
    for (; i + 2 <= cnt; i += 2) {  // unroll x2: 2x MLP on the latency chain
        int ea = eb[i], ebn = eb[i + 1];
        const __bf16* rowa = featb + (long)(ea & 0x1ffff) * 64;
        const __bf16* rowb = featb + (long)(ebn & 0x1ffff) * 64;
        bf16x8 a0 = *(const bf16x8*)(rowa + q * 8);
        bf16x8 a1 = *(const bf16x8*)(rowa + 32 + q * 8);
        bf16x8 b0v = *(const bf16x8*)(rowb + q * 8);
        bf16x8 b1v = *(const bf16x8*)(rowb + 32 + q * 8);
        int ta = (ea >> 17) & 1, tb = (ebn >> 17) & 1;
        c1 += ta + tb;
        float fa = (float)ta, fb = (float)tb;
#pragma unroll
        for (int j = 0; j < 8; j++) {
            float va = (float)a0[j], wa = (float)a1[j];
            float vb = (float)b0v[j], wb2 = (float)b1v[j];
            sA[j]     += va + vb;
            sA[8 + j] += wa + wb2;
            s1[j]     += fa * va + fb * vb;
            s1[8 + j] += fa * wa + fb * wb2;
        }
    }
    if (i < cnt) {
        int ea = eb[i];
        const __bf16* rowa = featb + (long)(ea & 0x1ffff) * 64;
        bf16x8 a0 = *(const bf16x8*)(rowa + q * 8);
        bf16x8 a1 = *(const bf16x8*)(rowa + 32 + q * 8);
        int ta = (ea >> 17) & 1;
        c1 += ta;
        float fa = (float)ta;
#pragma unroll
        for (int j = 0; j < 8; j++) {
            float va = (float)a0[j], wa = (float)a1[j];
            sA[j] += va;          sA[8 + j] += wa;
            s1[j] += fa * va;     s1[8 + j] += fa * wa;
        }
    }
    if (n >= NN) return;
    union { bf16x8 v; __bf16 e[8]; } u;
#pragma unroll
    for (int ch = 0; ch < 2; ch++) {
#pragma unroll
        for (int j = 0; j < 8; j++) u.e[j] = (__bf16)s1[ch * 8 + j];
        *(bf16x8*)(s1b + (long)n * 64 + ch * 32 + q * 8) = u.v;
#pragma unroll
        for (int j = 0; j < 8; j++) u.e[j] = (__bf16)(sA[ch * 8 + j] - s1[ch * 8 + j]);
        *(bf16x8*)(s0b + (long)n * 64 + ch * 32 + q * 8) = u.v;
    }
    if (q == 0) cc[n] = cnt | (c1 << 16);
}

// ---- MFMA stage: agg = S1@W0^T + S0@W1^T + count-biases; GRU; classifier ----
// R8: launch_bounds(256,2) + pin() cluster fences + XCD-aligned block map.
__global__ __launch_bounds__(256, 2) void k_mm(const __bf16* __restrict__ s1b,
                                               const __bf16* __restrict__ s0b,
                                               const __bf16* __restrict__ featb,
                                               const float* __restrict__ feat,
                                               const int* __restrict__ cc,
                                               const __bf16* __restrict__ wb,
                                               const float* __restrict__ b0,
                                               const float* __restrict__ b1,
                                               const float* __restrict__ bih,
                                               const float* __restrict__ bhh,
                                               const float* __restrict__ bout,
                                               float* __restrict__ out) {
    // per-wave LDS; sT (f32 [16][68]) and sH (bf16 [16][80]) union'd: sT dead
    // once Aag is built, before the first sH write (same-wave in-order LDS).
    __shared__ __align__(16) char smem[4][4352];
    int tid = threadIdx.x, lane = tid & 63, wave = tid >> 6;
    int L = lane & 15, q = lane >> 4;
    // XCD-aligned map: bucket b wrote s1b/s0b/cc on XCD b%8; land there.
    int j = blockIdx.x;
    int b = (j >> 4) * 8 + (j & 7);
    int s = (j >> 3) & 1;
    int n0 = b * NPB + s * 64 + wave * 16;
    if (n0 >= NN) return;
    float*  sT = (float*)smem[wave];
    __bf16* sH = (__bf16*)smem[wave];

    // --- issue coldest loads first (HBM-class), used last, not pinned ---
    float fvv[4][4];   // fp32 blend values for the GRU epilogue
#pragma unroll
    for (int nb = 0; nb < 4; nb++)
#pragma unroll
        for (int r = 0; r < 4; r++)
            fvv[nb][r] = feat[(long)(n0 + q * 4 + r) * 64 + nb * 16 + L];

    float fc1[4], fc0[4];
#pragma unroll
    for (int r = 0; r < 4; r++) {
        int v = cc[n0 + q * 4 + r];
        int c1 = v >> 16, ct = v & 0xffff;
        fc1[r] = (float)c1; fc0[r] = (float)(ct - c1);
    }

    // --- cluster 1: A-fragments + agg weight fragments, one pin barrier ---
    const __bf16* r1 = s1b + (long)(n0 + L) * 64;
    const __bf16* r0 = s0b + (long)(n0 + L) * 64;
    bf16x8 AS1[2] = { *(const bf16x8*)(r1 + q * 8), *(const bf16x8*)(r1 + 32 + q * 8) };
    bf16x8 AS0[2] = { *(const bf16x8*)(r0 + q * 8), *(const bf16x8*)(r0 + 32 + q * 8) };
    const __bf16* fr = featb + (long)(n0 + L) * 64;
    bf16x8 Aft[2] = { *(const bf16x8*)(fr + q * 8), *(const bf16x8*)(fr + 32 + q * 8) };

    const __bf16* w0b = wb, * w1b = wb + 4096;
    const __bf16* wihb = wb + 8192, * whhb = wb + 20480, * woutb = wb + 32768;

    bf16x8 W0F[4][2], W1F[4][2];
#pragma unroll
    for (int nb = 0; nb < 4; nb++)
#pragma unroll
        for (int ch = 0; ch < 2; ch++) {
            int off = (nb * 16 + L) * 64 + ch * 32 + q * 8;
            W0F[nb][ch] = *(const bf16x8*)(w0b + off);
            W1F[nb][ch] = *(const bf16x8*)(w1b + off);
        }
#pragma unroll
    for (int ch = 0; ch < 2; ch++) { pin(AS1[ch]); pin(AS0[ch]); pin(Aft[ch]); }
#pragma unroll
    for (int nb = 0; nb < 4; nb++)
#pragma unroll
        for (int ch = 0; ch < 2; ch++) { pin(W0F[nb][ch]); pin(W1F[nb][ch]); }

    f32x4 zz = {0.f, 0.f, 0.f, 0.f};
#pragma unroll
    for (int nb = 0; nb < 4; nb++) {
        f32x4 acc = zz;
#pragma unroll
        for (int ch = 0; ch < 2; ch++) {
            acc = MFMA16(AS1[ch], W0F[nb][ch], acc, 0, 0, 0);
            acc = MFMA16(AS0[ch], W1F[nb][ch], acc, 0, 0, 0);
        }
        float bs0 = b0[nb * 16 + L], bs1 = b1[nb * 16 + L];
#pragma unroll
        for (int r = 0; r < 4; r++)
            sT[(q * 4 + r) * 68 + nb * 16 + L] = acc[r] + fc1[r] * bs0 + fc0[r] * bs1;
    }

    // D->A transpose read (sT dead after this)
    bf16x8 Aag[2];
#pragma unroll
    for (int ch = 0; ch < 2; ch++) {
        union { bf16x8 v; __bf16 e[8]; } u;
#pragma unroll
        for (int j2 = 0; j2 < 8; j2++) u.e[j2] = (__bf16)sT[L * 68 + ch * 32 + q * 8 + j2];
        Aag[ch] = u.v;
    }

    // GRU gates [r,z,n]; per-nb: stage 12 B fragments, pin, pure-MFMA cluster
#pragma unroll
    for (int nb = 0; nb < 4; nb++) {
        int row = nb * 16 + L;
        bf16x8 WRi[2], WRh[2], WZi[2], WZh[2], WIN[2], WHN[2];
#pragma unroll
        for (int ch = 0; ch < 2; ch++) {
            int ko = ch * 32 + q * 8;
            WRi[ch] = *(const bf16x8*)(wihb + row * 64 + ko);
            WRh[ch] = *(const bf16x8*)(whhb + row * 64 + ko);
            WZi[ch] = *(const bf16x8*)(wihb + (64 + row) * 64 + ko);
            WZh[ch] = *(const bf16x8*)(whhb + (64 + row) * 64 + ko);
            WIN[ch] = *(const bf16x8*)(wihb + (128 + row) * 64 + ko);
            WHN[ch] = *(const bf16x8*)(whhb + (128 + row) * 64 + ko);
        }
#pragma unroll
        for (int ch = 0; ch < 2; ch++) {
            pin(WRi[ch]); pin(WRh[ch]); pin(WZi[ch]);
            pin(WZh[ch]); pin(WIN[ch]); pin(WHN[ch]);
        }
        f32x4 aR = zz, aZ = zz, aIN = zz, aHN = zz;
#pragma unroll
        for (int ch = 0; ch < 2; ch++) {
            aR  = MFMA16(Aag[ch], WRi[ch], aR, 0, 0, 0);
            aR  = MFMA16(Aft[ch], WRh[ch], aR, 0, 0, 0);
            aZ  = MFMA16(Aag[ch], WZi[ch], aZ, 0, 0, 0);
            aZ  = MFMA16(Aft[ch], WZh[ch], aZ, 0, 0, 0);
            aIN = MFMA16(Aag[ch], WIN[ch], aIN, 0, 0, 0);
            aHN = MFMA16(Aft[ch], WHN[ch], aHN, 0, 0, 0);
        }
        int h = row;
        float br  = bih[h] + bhh[h];
        float bz  = bih[64 + h] + bhh[64 + h];
        float bin = bih[128 + h];
        float bhn = bhh[128 + h];
#pragma unroll
        for (int r = 0; r < 4; r++) {
            float rv = sigmoidf_(aR[r] + br);
            float zv = sigmoidf_(aZ[r] + bz);
            float nv = tanhf(aIN[r] + bin + rv * (aHN[r] + bhn));
            float fv = fvv[nb][r];  // fp32 blend for accuracy
            sH[(q * 4 + r) * 80 + h] = (__bf16)((1.0f - zv) * nv + zv * fv);
        }
    }

    // out = h @ W_out^T + b_out
    bf16x8 Ah0 = *(const bf16x8*)&sH[L * 80 + q * 8];
    bf16x8 Ah1 = *(const bf16x8*)&sH[L * 80 + 32 + q * 8];
    bf16x8 Bo0 = *(const bf16x8*)(woutb + L * 64 + q * 8);
    bf16x8 Bo1 = *(const bf16x8*)(woutb + L * 64 + 32 + q * 8);
    f32x4 o = zz;
    o = MFMA16(Ah0, Bo0, o, 0, 0, 0);
    o = MFMA16(Ah1, Bo1, o, 0, 0, 0);
    float bo = bout[L];
#pragma unroll
    for (int r = 0; r < 4; r++)
        out[(long)(n0 + q * 4 + r) * 16 + L] = o[r] + bo;
}

extern "C" void kernel_launch(void* const* d_in, const int* in_sizes, int n_in,
                              void* d_out, int out_size, void* d_ws, size_t ws_size,
                              hipStream_t stream) {
    const float* features = (const float*)d_in[0];
    const int*   src      = (const int*)d_in[1];
    const int*   dst      = (const int*)d_in[2];
    const unsigned char* etype = (const unsigned char*)d_in[3];
    const float* W0   = (const float*)d_in[4];
    const float* b0   = (const float*)d_in[5];
    const float* W1   = (const float*)d_in[6];
    const float* b1   = (const float*)d_in[7];
    const float* Wih  = (const float*)d_in[8];
    const float* Whh  = (const float*)d_in[9];
    const float* bih  = (const float*)d_in[10];
    const float* bhh  = (const float*)d_in[11];
    const float* Wout = (const float*)d_in[12];
    const float* bout = (const float*)d_in[13];
    float* out = (float*)d_out;

    char* ws = (char*)d_ws;
    size_t off = 0;
    __bf16* featb     = (__bf16*)(ws + off); off += (size_t)NN * 64 * 2;     // 12.8 MB
    int*    region    = (int*)(ws + off);    off += (size_t)BB * ECAP * 4;   // 5.0 MB
    int*    hist      = (int*)(ws + off);    off += (size_t)NB * BB * 4;     // 766 KB
    int*    blockBase = (int*)(ws + off);    off += (size_t)NB * BB * 4;     // 766 KB
    int*    bucketCnt = (int*)(ws + off);    off += (size_t)BB * 4;
    int*    cc        = (int*)(ws + off);    off += (size_t)NN * 4;
    __bf16* s1b       = (__bf16*)(ws + off); off += (size_t)NN * 64 * 2;     // 12.8 MB
    __bf16* s0b       = (__bf16*)(ws + off); off += (size_t)NN * 64 * 2;     // 12.8 MB
    __bf16* wb        = (__bf16*)(ws + off); off += 33792 * 2;
    int*    flag      = (int*)(ws + off);

    k_init<<<6383, 256, 0, stream>>>(etype, features, W0, W1, Wih, Whh, Wout,
                                     featb, wb, flag);
    k_s1<<<NB, 512, 0, stream>>>(dst, hist);
    k_s2<<<(BB + 3) / 4, 256, 0, stream>>>(hist, blockBase, bucketCnt);
    k_s3<<<NB, 512, 0, stream>>>(src, dst, etype, flag, blockBase, region);
    k_g<<<BB, 512, 0, stream>>>(featb, region, bucketCnt, s1b, s0b, cc);
    // 1568 = 784 buckets-padded * 2 halves (XCD-aligned bijective map)
    k_mm<<<1568, 256, 0, stream>>>(s1b, s0b, featb, features, cc, wb,
                                   b0, b1, bih, bhh, bout, out);
}

// Round 3
// 187.290 us; speedup vs baseline: 1.1159x; 1.1159x over previous
//
#include <hip/hip_runtime.h>

// GGNN on MI355X. N=100000, E=1000000, H=M=64, C=16.
// R6: deterministic bucket sort (k_s1 histogram / k_s2 scan / k_s3 place /
//     k_g gather / k_mm MFMA GRU+head). ws layout unchanged.
// R7: launch_bounds min-waves -> compiler re-sank staged loads; 64us.
// R8 post-mortem: pin() fences + XCD map REGRESSED (77us): fences drain all
//     cluster loads before any MFMA; XCD map no FETCH delta. Root cause of
//     the k_mm stall is structural: every wave streams the ENTIRE 64KB
//     weight set through the vector pipe as ~80 dependent 16B loads; that
//     can't be register-staged (256 VGPR/lane equivalent).
// R9: weights -> LDS. 512-thr block (8 waves, 1 bucket = 128 nodes), stage
//     all 33792 bf16 weights into LDS once per block (9 loads/thread),
//     XOR-swizzled (byte ^= ((byte>>7)&7)<<4) so B-fragment ds_read_b128
//     (lane stride 128B) is conflict-free. All MFMA B operands now come
//     from LDS; per-wave global loads drop 110 -> ~32. LDS 100KB -> 1
//     block/CU; grid 782. Math order identical -> absmax 0.0078125 exactly.
// ws: [featb | region 782*1600 | hist 245*782 | blockBase 245*782 |
//      bucketCnt 782 | cc N | s1b | s0b | wb | flag]

typedef __bf16 bf16x8 __attribute__((ext_vector_type(8)));
typedef float  f32x4  __attribute__((ext_vector_type(4)));
typedef int    i32x4  __attribute__((ext_vector_type(4)));

#define MFMA16 __builtin_amdgcn_mfma_f32_16x16x32_bf16
#define NN   100000
#define EE   1000000
#define BB   782     // buckets (dst >> 7)
#define NPB  128     // nodes per bucket
#define ECAP 1600    // bucket region capacity (mean 1280, +9 sigma)
#define DCAP 48      // per-node degree cap (Poisson(10), P(>=48) ~ 1e-17)
#define CSTRD 49     // CSR LDS stride (conflict pad)
#define NB   245     // histogram blocks (4096 edges each)
#define NW   33792   // total weights (w0 4096 | w1 4096 | wih 12288 | whh 12288 | wout 1024)

__device__ __forceinline__ float sigmoidf_(float x) {
    return 1.0f / (1.0f + __expf(-x));
}

// swizzled LDS weight fragment read: e = element offset (16B-aligned *2).
// swz spreads the 128B-row-stride fragment pattern across banks (T2).
__device__ __forceinline__ bf16x8 ldw(const __bf16* w, int e) {
    int bo = e * 2;
    bo ^= ((bo >> 7) & 7) << 4;
    return *(const bf16x8*)((const char*)w + bo);
}

// ---- fused init: dtype detect / weight cvt / feature cvt ----
__global__ __launch_bounds__(256) void k_init(const unsigned char* __restrict__ et,
                                              const float* __restrict__ feat,
                                              const float* __restrict__ w0,
                                              const float* __restrict__ w1,
                                              const float* __restrict__ wih,
                                              const float* __restrict__ whh,
                                              const float* __restrict__ wout,
                                              __bf16* __restrict__ featb,
                                              __bf16* __restrict__ wb,
                                              int* __restrict__ flag) {
    int b = blockIdx.x, tid = threadIdx.x;
    if (b == 0) {
        // flag=1 iff any nonzero byte at offset%4!=0 in first 64KB (bool
        // storage); int32 0/1 storage has bytes 1..3 of every word zero.
        __shared__ int sdet[4];
        const i32x4* p = (const i32x4*)et + tid * 16;  // 256 B per thread
        unsigned acc = 0;
#pragma unroll
        for (int j = 0; j < 16; j++) {
            i32x4 w = p[j];
            acc |= (unsigned)(w[0] | w[1] | w[2] | w[3]) & 0xffffff00u;
        }
        unsigned long long m = __ballot(acc != 0);
        if ((tid & 63) == 0) sdet[tid >> 6] = (m != 0ULL);
        __syncthreads();
        if (tid == 0) *flag = sdet[0] | sdet[1] | sdet[2] | sdet[3];
        return;
    }
    if (b < 133) {  // 132 blocks * 256 = 33792 weights exactly
        int i = (b - 1) * 256 + tid;
        float v;
        if      (i < 4096)  v = w0[i];
        else if (i < 8192)  v = w1[i - 4096];
        else if (i < 20480) v = wih[i - 8192];
        else if (i < 32768) v = whh[i - 20480];
        else                v = wout[i - 32768];
        wb[i] = (__bf16)v;
        return;
    }
    long i = ((long)(b - 133) * 256 + tid) * 4;
    if (i >= (long)NN * 64) return;
    f32x4 v = *(const f32x4*)(feat + i);
    union { __bf16 e[4]; unsigned long long u; } o;
#pragma unroll
    for (int j = 0; j < 4; j++) o.e[j] = (__bf16)v[j];
    *(unsigned long long*)(featb + i) = o.u;
}

// ---- s1: per-block bucket histogram (LDS non-returning atomics only) ----
__global__ __launch_bounds__(512) void k_s1(const int* __restrict__ dst,
                                            int* __restrict__ hist) {
    __shared__ int cnt[BB];
    int blk = blockIdx.x, tid = threadIdx.x;
    for (int i = tid; i < BB; i += 512) cnt[i] = 0;
    __syncthreads();
    long e0 = (long)blk * 4096 + tid * 8;  // EE % 8 == 0: no scalar tail
    if (e0 < EE) {
        i32x4 d0 = *(const i32x4*)(dst + e0);
        i32x4 d1 = *(const i32x4*)(dst + e0 + 4);
#pragma unroll
        for (int j = 0; j < 4; j++) atomicAdd(&cnt[d0[j] >> 7], 1);
#pragma unroll
        for (int j = 0; j < 4; j++) atomicAdd(&cnt[d1[j] >> 7], 1);
    }
    __syncthreads();
    for (int i = tid; i < BB; i += 512) hist[blk * BB + i] = cnt[i];
}

// ---- s2: exclusive scan over blocks per bucket (1 wave/bucket) ----
__global__ __launch_bounds__(256) void k_s2(const int* __restrict__ hist,
                                            int* __restrict__ blockBase,
                                            int* __restrict__ bucketCnt) {
    int b = blockIdx.x * 4 + (threadIdx.x >> 6);
    int lane = threadIdx.x & 63;
    if (b >= BB) return;
    int carry = 0;
    for (int c = 0; c < 4; c++) {       // ceil(245/64) = 4 chunks
        int blk = c * 64 + lane;
        int v = (blk < NB) ? hist[blk * BB + b] : 0;
        int x = v;
#pragma unroll
        for (int off = 1; off < 64; off <<= 1) {
            int y = __shfl_up(x, off, 64);
            if (lane >= off) x += y;
        }
        if (blk < NB) blockBase[blk * BB + b] = x - v + carry;
        carry += __shfl(x, 63, 64);
    }
    if (lane == 0) bucketCnt[b] = carry;
}

// ---- s3: place edges deterministically (LDS cursors seeded w/ blockBase) ----
__global__ __launch_bounds__(512) void k_s3(const int* __restrict__ src,
                                            const int* __restrict__ dst,
                                            const unsigned char* __restrict__ etype,
                                            const int* __restrict__ flag,
                                            const int* __restrict__ blockBase,
                                            int* __restrict__ region) {
    __shared__ int cur[BB];
    int blk = blockIdx.x, tid = threadIdx.x;
    for (int i = tid; i < BB; i += 512) cur[i] = blockBase[blk * BB + i];
    __syncthreads();
    long e0 = (long)blk * 4096 + tid * 8;
    if (e0 >= EE) return;
    i32x4 s0 = *(const i32x4*)(src + e0);
    i32x4 s1 = *(const i32x4*)(src + e0 + 4);
    i32x4 d0 = *(const i32x4*)(dst + e0);
    i32x4 d1 = *(const i32x4*)(dst + e0 + 4);
    int t[8];
    if (*flag) {  // 1-byte bool storage
        unsigned long long w = *(const unsigned long long*)(etype + e0);
#pragma unroll
        for (int j = 0; j < 8; j++) t[j] = (int)((w >> (8 * j)) & 0xff);
    } else {      // int32 storage
        i32x4 w0 = *(const i32x4*)((const int*)etype + e0);
        i32x4 w1 = *(const i32x4*)((const int*)etype + e0 + 4);
#pragma unroll
        for (int j = 0; j < 4; j++) { t[j] = w0[j]; t[4 + j] = w1[j]; }
    }
    int dd[8] = {d0[0], d0[1], d0[2], d0[3], d1[0], d1[1], d1[2], d1[3]};
    int ss[8] = {s0[0], s0[1], s0[2], s0[3], s1[0], s1[1], s1[2], s1[3]};
#pragma unroll
    for (int j = 0; j < 8; j++) {
        int b  = dd[j] >> 7;
        int nl = dd[j] & 127;
        int r  = atomicAdd(&cur[b], 1);  // LDS returning atomic: fast
        if (r < ECAP)
            region[b * ECAP + r] = (nl << 18) | ((t[j] ? 1 : 0) << 17) | ss[j];
    }
}

// ---- gather: per-bucket CSR build in LDS, then 8 waves x 16 nodes ----
__global__ __launch_bounds__(512) void k_g(const __bf16* __restrict__ featb,
                                           const int* __restrict__ region,
                                           const int* __restrict__ bucketCnt,
                                           __bf16* __restrict__ s1b,
                                           __bf16* __restrict__ s0b,
                                           int* __restrict__ cc) {
    __shared__ int ncnt[NPB];
    __shared__ int csr[NPB * CSTRD];  // stride 49: breaks 2-bank aliasing
    int b = blockIdx.x, tid = threadIdx.x;
    int cntE = min(bucketCnt[b], ECAP);
    if (tid < NPB) ncnt[tid] = 0;
    __syncthreads();
    const int* reg = region + b * ECAP;
    for (int i = tid; i < cntE; i += 512) {
        int rec = reg[i];
        int nl = rec >> 18;
        int r = atomicAdd(&ncnt[nl], 1);
        if (r < DCAP) csr[nl * CSTRD + r] = rec & 0x3ffff;  // type|src
    }
    __syncthreads();

    int lane = tid & 63, wave = tid >> 6;
    int L = lane & 15, q = lane >> 4;
    int nl = wave * 16 + L;        // 8 waves x 16 nodes = 128
    int n = b * NPB + nl;
    int cnt = (n < NN) ? min(ncnt[nl], DCAP) : 0;
    const int* eb = &csr[nl * CSTRD];

    float sA[16], s1[16];
#pragma unroll
    for (int j = 0; j < 16; j++) { sA[j] = 0.f; s1[j] = 0.f; }
    int c1 = 0;
    int i = 0;
    for (; i + 2 <= cnt; i += 2) {  // unroll x2: 2x MLP on the latency chain
        int ea = eb[i], ebn = eb[i + 1];
        const __bf16* rowa = featb + (long)(ea & 0x1ffff) * 64;
        const __bf16* rowb = featb + (long)(ebn & 0x1ffff) * 64;
        bf16x8 a0 = *(const bf16x8*)(rowa + q * 8);
        bf16x8 a1 = *(const bf16x8*)(rowa + 32 + q * 8);
        bf16x8 b0v = *(const bf16x8*)(rowb + q * 8);
        bf16x8 b1v = *(const bf16x8*)(rowb + 32 + q * 8);
        int ta = (ea >> 17) & 1, tb = (ebn >> 17) & 1;
        c1 += ta + tb;
        float fa = (float)ta, fb = (float)tb;
#pragma unroll
        for (int j = 0; j < 8; j++) {
            float va = (float)a0[j], wa = (float)a1[j];
            float vb = (float)b0v[j], wb2 = (float)b1v[j];
            sA[j]     += va + vb;
            sA[8 + j] += wa + wb2;
            s1[j]     += fa * va + fb * vb;
            s1[8 + j] += fa * wa + fb * wb2;
        }
    }
    if (i < cnt) {
        int ea = eb[i];
        const __bf16* rowa = featb + (long)(ea & 0x1ffff) * 64;
        bf16x8 a0 = *(const bf16x8*)(rowa + q * 8);
        bf16x8 a1 = *(const bf16x8*)(rowa + 32 + q * 8);
        int ta = (ea >> 17) & 1;
        c1 += ta;
        float fa = (float)ta;
#pragma unroll
        for (int j = 0; j < 8; j++) {
            float va = (float)a0[j], wa = (float)a1[j];
            sA[j] += va;          sA[8 + j] += wa;
            s1[j] += fa * va;     s1[8 + j] += fa * wa;
        }
    }
    if (n >= NN) return;
    union { bf16x8 v; __bf16 e[8]; } u;
#pragma unroll
    for (int ch = 0; ch < 2; ch++) {
#pragma unroll
        for (int j = 0; j < 8; j++) u.e[j] = (__bf16)s1[ch * 8 + j];
        *(bf16x8*)(s1b + (long)n * 64 + ch * 32 + q * 8) = u.v;
#pragma unroll
        for (int j = 0; j < 8; j++) u.e[j] = (__bf16)(sA[ch * 8 + j] - s1[ch * 8 + j]);
        *(bf16x8*)(s0b + (long)n * 64 + ch * 32 + q * 8) = u.v;
    }
    if (q == 0) cc[n] = cnt | (c1 << 16);
}

// ---- MFMA stage: agg = S1@W0^T + S0@W1^T + count-biases; GRU; classifier ----
// R9: 8 waves / 128 nodes per block; all weights staged to LDS (swizzled).
__global__ __launch_bounds__(512, 2) void k_mm(const __bf16* __restrict__ s1b,
                                               const __bf16* __restrict__ s0b,
                                               const __bf16* __restrict__ featb,
                                               const float* __restrict__ feat,
                                               const int* __restrict__ cc,
                                               const __bf16* __restrict__ wb,
                                               const float* __restrict__ b0,
                                               const float* __restrict__ b1,
                                               const float* __restrict__ bih,
                                               const float* __restrict__ bhh,
                                               const float* __restrict__ bout,
                                               float* __restrict__ out) {
    // wlds: all weights, XOR-swizzled 16B blocks (see ldw()).
    // smem: per-wave sT (f32 [16][68]) / sH (bf16 [16][80]) union; sT dead
    // once Aag is built, before the first sH write (same-wave in-order LDS).
    __shared__ __align__(16) __bf16 wlds[NW];
    __shared__ __align__(16) char smem[8][4352];
    int tid = threadIdx.x, lane = tid & 63, wave = tid >> 6;
    int L = lane & 15, q = lane >> 4;
    int n0 = blockIdx.x * NPB + wave * 16;

    // per-wave global loads issued first: complete under the staging phase
    bf16x8 AS1[2], AS0[2], Aft[2];
    float fvv[4][4], fc1[4], fc0[4];
    if (n0 < NN) {
        const __bf16* r1 = s1b + (long)(n0 + L) * 64;
        const __bf16* r0 = s0b + (long)(n0 + L) * 64;
        const __bf16* fr = featb + (long)(n0 + L) * 64;
        AS1[0] = *(const bf16x8*)(r1 + q * 8);  AS1[1] = *(const bf16x8*)(r1 + 32 + q * 8);
        AS0[0] = *(const bf16x8*)(r0 + q * 8);  AS0[1] = *(const bf16x8*)(r0 + 32 + q * 8);
        Aft[0] = *(const bf16x8*)(fr + q * 8);  Aft[1] = *(const bf16x8*)(fr + 32 + q * 8);
#pragma unroll
        for (int nb = 0; nb < 4; nb++)
#pragma unroll
            for (int r = 0; r < 4; r++)
                fvv[nb][r] = feat[(long)(n0 + q * 4 + r) * 64 + nb * 16 + L];
#pragma unroll
        for (int r = 0; r < 4; r++) {
            int v = cc[n0 + q * 4 + r];
            int c1 = v >> 16, ct = v & 0xffff;
            fc1[r] = (float)c1; fc0[r] = (float)(ct - c1);
        }
    }

    // cooperative weight staging: 33792 bf16, swizzled 16B blocks
    for (int k = tid * 8; k < NW; k += 512 * 8) {
        bf16x8 v = *(const bf16x8*)(wb + k);
        int bo = k * 2;
        int so = bo ^ (((bo >> 7) & 7) << 4);
        *(bf16x8*)((char*)wlds + so) = v;
    }
    __syncthreads();
    if (n0 >= NN) return;

    float*  sT = (float*)smem[wave];
    __bf16* sH = (__bf16*)smem[wave];
    f32x4 zz = {0.f, 0.f, 0.f, 0.f};

    // agg = S1@W0^T + S0@W1^T + per-count biases
#pragma unroll
    for (int nb = 0; nb < 4; nb++) {
        f32x4 acc = zz;
#pragma unroll
        for (int ch = 0; ch < 2; ch++) {
            int off = (nb * 16 + L) * 64 + ch * 32 + q * 8;
            acc = MFMA16(AS1[ch], ldw(wlds, off), acc, 0, 0, 0);
            acc = MFMA16(AS0[ch], ldw(wlds, 4096 + off), acc, 0, 0, 0);
        }
        float bs0 = b0[nb * 16 + L], bs1 = b1[nb * 16 + L];
#pragma unroll
        for (int r = 0; r < 4; r++)
            sT[(q * 4 + r) * 68 + nb * 16 + L] = acc[r] + fc1[r] * bs0 + fc0[r] * bs1;
    }

    // D->A transpose read (sT dead after this)
    bf16x8 Aag[2];
#pragma unroll
    for (int ch = 0; ch < 2; ch++) {
        union { bf16x8 v; __bf16 e[8]; } u;
#pragma unroll
        for (int j2 = 0; j2 < 8; j2++) u.e[j2] = (__bf16)sT[L * 68 + ch * 32 + q * 8 + j2];
        Aag[ch] = u.v;
    }

    // GRU gates [r,z,n]; B fragments from LDS (wih @8192, whh @20480)
#pragma unroll
    for (int nb = 0; nb < 4; nb++) {
        int row = nb * 16 + L;
        f32x4 aR = zz, aZ = zz, aIN = zz, aHN = zz;
#pragma unroll
        for (int ch = 0; ch < 2; ch++) {
            int ko = ch * 32 + q * 8;
            aR  = MFMA16(Aag[ch], ldw(wlds, 8192  + row * 64 + ko), aR, 0, 0, 0);
            aR  = MFMA16(Aft[ch], ldw(wlds, 20480 + row * 64 + ko), aR, 0, 0, 0);
            aZ  = MFMA16(Aag[ch], ldw(wlds, 8192  + (64 + row) * 64 + ko), aZ, 0, 0, 0);
            aZ  = MFMA16(Aft[ch], ldw(wlds, 20480 + (64 + row) * 64 + ko), aZ, 0, 0, 0);
            aIN = MFMA16(Aag[ch], ldw(wlds, 8192  + (128 + row) * 64 + ko), aIN, 0, 0, 0);
            aHN = MFMA16(Aft[ch], ldw(wlds, 20480 + (128 + row) * 64 + ko), aHN, 0, 0, 0);
        }
        int h = row;
        float br  = bih[h] + bhh[h];
        float bz  = bih[64 + h] + bhh[64 + h];
        float bin = bih[128 + h];
        float bhn = bhh[128 + h];
#pragma unroll
        for (int r = 0; r < 4; r++) {
            float rv = sigmoidf_(aR[r] + br);
            float zv = sigmoidf_(aZ[r] + bz);
            float nv = tanhf(aIN[r] + bin + rv * (aHN[r] + bhn));
            float fv = fvv[nb][r];  // fp32 blend for accuracy
            sH[(q * 4 + r) * 80 + h] = (__bf16)((1.0f - zv) * nv + zv * fv);
        }
    }

    // out = h @ W_out^T + b_out (wout @32768)
    bf16x8 Ah0 = *(const bf16x8*)&sH[L * 80 + q * 8];
    bf16x8 Ah1 = *(const bf16x8*)&sH[L * 80 + 32 + q * 8];
    bf16x8 Bo0 = ldw(wlds, 32768 + L * 64 + q * 8);
    bf16x8 Bo1 = ldw(wlds, 32768 + L * 64 + 32 + q * 8);
    f32x4 o = zz;
    o = MFMA16(Ah0, Bo0, o, 0, 0, 0);
    o = MFMA16(Ah1, Bo1, o, 0, 0, 0);
    float bo = bout[L];
#pragma unroll
    for (int r = 0; r < 4; r++)
        out[(long)(n0 + q * 4 + r) * 16 + L] = o[r] + bo;
}

extern "C" void kernel_launch(void* const* d_in, const int* in_sizes, int n_in,
                              void* d_out, int out_size, void* d_ws, size_t ws_size,
                              hipStream_t stream) {
    const float* features = (const float*)d_in[0];
    const int*   src      = (const int*)d_in[1];
    const int*   dst      = (const int*)d_in[2];
    const unsigned char* etype = (const unsigned char*)d_in[3];
    const float* W0   = (const float*)d_in[4];
    const float* b0   = (const float*)d_in[5];
    const float* W1   = (const float*)d_in[6];
    const float* b1   = (const float*)d_in[7];
    const float* Wih  = (const float*)d_in[8];
    const float* Whh  = (const float*)d_in[9];
    const float* bih  = (const float*)d_in[10];
    const float* bhh  = (const float*)d_in[11];
    const float* Wout = (const float*)d_in[12];
    const float* bout = (const float*)d_in[13];
    float* out = (float*)d_out;

    char* ws = (char*)d_ws;
    size_t off = 0;
    __bf16* featb     = (__bf16*)(ws + off); off += (size_t)NN * 64 * 2;     // 12.8 MB
    int*    region    = (int*)(ws + off);    off += (size_t)BB * ECAP * 4;   // 5.0 MB
    int*    hist      = (int*)(ws + off);    off += (size_t)NB * BB * 4;     // 766 KB
    int*    blockBase = (int*)(ws + off);    off += (size_t)NB * BB * 4;     // 766 KB
    int*    bucketCnt = (int*)(ws + off);    off += (size_t)BB * 4;
    int*    cc        = (int*)(ws + off);    off += (size_t)NN * 4;
    __bf16* s1b       = (__bf16*)(ws + off); off += (size_t)NN * 64 * 2;     // 12.8 MB
    __bf16* s0b       = (__bf16*)(ws + off); off += (size_t)NN * 64 * 2;     // 12.8 MB
    __bf16* wb        = (__bf16*)(ws + off); off += 33792 * 2;
    int*    flag      = (int*)(ws + off);

    k_init<<<6383, 256, 0, stream>>>(etype, features, W0, W1, Wih, Whh, Wout,
                                     featb, wb, flag);
    k_s1<<<NB, 512, 0, stream>>>(dst, hist);
    k_s2<<<(BB + 3) / 4, 256, 0, stream>>>(hist, blockBase, bucketCnt);
    k_s3<<<NB, 512, 0, stream>>>(src, dst, etype, flag, blockBase, region);
    k_g<<<BB, 512, 0, stream>>>(featb, region, bucketCnt, s1b, s0b, cc);
    // one bucket (128 nodes) per block, weights LDS-resident
    k_mm<<<BB, 512, 0, stream>>>(s1b, s0b, featb, features, cc, wb,
                                 b0, b1, bih, bhh, bout, out);
}

// Round 4
// 185.264 us; speedup vs baseline: 1.1281x; 1.0109x over previous
//
#include <hip/hip_runtime.h>

// GGNN on MI355X. N=100000, E=1000000, H=M=64, C=16.
// R6: deterministic bucket sort (k_s1 hist / k_s2 scan / k_s3 place /
//     k_g gather / k_mm MFMA GRU+head).
// R9: weights->LDS killed the per-wave 64KB weight stream (77->45us) but
//     100KB LDS -> 1 block/CU -> Occupancy 14.9%: latency exposed.
// R10: (a) agg transpose buffer stored as bf16 (value identical: it was
//      converted to bf16 on read anyway); sT/sH unified [16][80] bf16 ->
//      20.5KB/block. (b) only wih+whh (49KB, the 48 GRU ds-reads) staged in
//      LDS; w0/w1/wout stay global (L2-resident 67KB). LDS 69632B -> 2
//      blocks/CU, 16 waves. launch_bounds(512,4) caps VGPR 128. (c) cc read
//      vectorized i32x4. (d) k_s1 fused into k_init as 245 extra blocks
//      (independent inputs; identical histogram math). All arithmetic
//      bit-identical -> absmax must stay 0.0078125 exactly.
// ws: [featb | region 782*1600 | hist 245*782 | blockBase 245*782 |
//      bucketCnt 782 | cc N | s1b | s0b | wb | flag]

typedef __bf16 bf16x8 __attribute__((ext_vector_type(8)));
typedef float  f32x4  __attribute__((ext_vector_type(4)));
typedef int    i32x4  __attribute__((ext_vector_type(4)));

#define MFMA16 __builtin_amdgcn_mfma_f32_16x16x32_bf16
#define NN   100000
#define EE   1000000
#define BB   782     // buckets (dst >> 7)
#define NPB  128     // nodes per bucket
#define ECAP 1600    // bucket region capacity (mean 1280, +9 sigma)
#define DCAP 48      // per-node degree cap (Poisson(10), P(>=48) ~ 1e-17)
#define CSTRD 49     // CSR LDS stride (conflict pad)
#define NB   245     // histogram blocks (4096 edges each)
#define NWL  24576   // LDS-staged weights: wih (12288) + whh (12288)

__device__ __forceinline__ float sigmoidf_(float x) {
    return 1.0f / (1.0f + __expf(-x));
}

// swizzled LDS weight fragment read: e = element offset (16B-aligned).
// XOR of row bits into the 16B-slot bits: conflict-free for the 128B-row-
// stride fragment pattern (T2).
__device__ __forceinline__ bf16x8 ldw(const __bf16* w, int e) {
    int bo = e * 2;
    bo ^= ((bo >> 7) & 7) << 4;
    return *(const bf16x8*)((const char*)w + bo);
}

// ---- fused init: dtype detect / weight cvt / feature cvt / dst histogram ----
__global__ __launch_bounds__(256) void k_init(const unsigned char* __restrict__ et,
                                              const float* __restrict__ feat,
                                              const int* __restrict__ dst,
                                              const float* __restrict__ w0,
                                              const float* __restrict__ w1,
                                              const float* __restrict__ wih,
                                              const float* __restrict__ whh,
                                              const float* __restrict__ wout,
                                              __bf16* __restrict__ featb,
                                              __bf16* __restrict__ wb,
                                              int* __restrict__ hist,
                                              int* __restrict__ flag) {
    int b = blockIdx.x, tid = threadIdx.x;
    if (b == 0) {
        // flag=1 iff any nonzero byte at offset%4!=0 in first 64KB (bool
        // storage); int32 0/1 storage has bytes 1..3 of every word zero.
        __shared__ int sdet[4];
        const i32x4* p = (const i32x4*)et + tid * 16;  // 256 B per thread
        unsigned acc = 0;
#pragma unroll
        for (int j = 0; j < 16; j++) {
            i32x4 w = p[j];
            acc |= (unsigned)(w[0] | w[1] | w[2] | w[3]) & 0xffffff00u;
        }
        unsigned long long m = __ballot(acc != 0);
        if ((tid & 63) == 0) sdet[tid >> 6] = (m != 0ULL);
        __syncthreads();
        if (tid == 0) *flag = sdet[0] | sdet[1] | sdet[2] | sdet[3];
        return;
    }
    if (b < 133) {  // 132 blocks * 256 = 33792 weights exactly
        int i = (b - 1) * 256 + tid;
        float v;
        if      (i < 4096)  v = w0[i];
        else if (i < 8192)  v = w1[i - 4096];
        else if (i < 20480) v = wih[i - 8192];
        else if (i < 32768) v = whh[i - 20480];
        else                v = wout[i - 32768];
        wb[i] = (__bf16)v;
        return;
    }
    if (b >= 6383) {  // fused k_s1: per-block dst-bucket histogram
        __shared__ int cnt[BB];
        int hb = b - 6383;
        for (int i = tid; i < BB; i += 256) cnt[i] = 0;
        __syncthreads();
        long e0 = (long)hb * 4096 + tid * 16;
#pragma unroll
        for (int g = 0; g < 2; g++) {
            long e = e0 + g * 8;
            if (e < EE) {
                i32x4 d0 = *(const i32x4*)(dst + e);
                i32x4 d1 = *(const i32x4*)(dst + e + 4);
#pragma unroll
                for (int j = 0; j < 4; j++) atomicAdd(&cnt[d0[j] >> 7], 1);
#pragma unroll
                for (int j = 0; j < 4; j++) atomicAdd(&cnt[d1[j] >> 7], 1);
            }
        }
        __syncthreads();
        for (int i = tid; i < BB; i += 256) hist[hb * BB + i] = cnt[i];
        return;
    }
    long i = ((long)(b - 133) * 256 + tid) * 4;
    if (i >= (long)NN * 64) return;
    f32x4 v = *(const f32x4*)(feat + i);
    union { __bf16 e[4]; unsigned long long u; } o;
#pragma unroll
    for (int j = 0; j < 4; j++) o.e[j] = (__bf16)v[j];
    *(unsigned long long*)(featb + i) = o.u;
}

// ---- s2: exclusive scan over blocks per bucket (1 wave/bucket) ----
__global__ __launch_bounds__(256) void k_s2(const int* __restrict__ hist,
                                            int* __restrict__ blockBase,
                                            int* __restrict__ bucketCnt) {
    int b = blockIdx.x * 4 + (threadIdx.x >> 6);
    int lane = threadIdx.x & 63;
    if (b >= BB) return;
    int carry = 0;
    for (int c = 0; c < 4; c++) {       // ceil(245/64) = 4 chunks
        int blk = c * 64 + lane;
        int v = (blk < NB) ? hist[blk * BB + b] : 0;
        int x = v;
#pragma unroll
        for (int off = 1; off < 64; off <<= 1) {
            int y = __shfl_up(x, off, 64);
            if (lane >= off) x += y;
        }
        if (blk < NB) blockBase[blk * BB + b] = x - v + carry;
        carry += __shfl(x, 63, 64);
    }
    if (lane == 0) bucketCnt[b] = carry;
}

// ---- s3: place edges deterministically (LDS cursors seeded w/ blockBase) ----
__global__ __launch_bounds__(512) void k_s3(const int* __restrict__ src,
                                            const int* __restrict__ dst,
                                            const unsigned char* __restrict__ etype,
                                            const int* __restrict__ flag,
                                            const int* __restrict__ blockBase,
                                            int* __restrict__ region) {
    __shared__ int cur[BB];
    int blk = blockIdx.x, tid = threadIdx.x;
    for (int i = tid; i < BB; i += 512) cur[i] = blockBase[blk * BB + i];
    __syncthreads();
    long e0 = (long)blk * 4096 + tid * 8;
    if (e0 >= EE) return;
    i32x4 s0 = *(const i32x4*)(src + e0);
    i32x4 s1 = *(const i32x4*)(src + e0 + 4);
    i32x4 d0 = *(const i32x4*)(dst + e0);
    i32x4 d1 = *(const i32x4*)(dst + e0 + 4);
    int t[8];
    if (*flag) {  // 1-byte bool storage
        unsigned long long w = *(const unsigned long long*)(etype + e0);
#pragma unroll
        for (int j = 0; j < 8; j++) t[j] = (int)((w >> (8 * j)) & 0xff);
    } else {      // int32 storage
        i32x4 w0 = *(const i32x4*)((const int*)etype + e0);
        i32x4 w1 = *(const i32x4*)((const int*)etype + e0 + 4);
#pragma unroll
        for (int j = 0; j < 4; j++) { t[j] = w0[j]; t[4 + j] = w1[j]; }
    }
    int dd[8] = {d0[0], d0[1], d0[2], d0[3], d1[0], d1[1], d1[2], d1[3]};
    int ss[8] = {s0[0], s0[1], s0[2], s0[3], s1[0], s1[1], s1[2], s1[3]};
#pragma unroll
    for (int j = 0; j < 8; j++) {
        int b  = dd[j] >> 7;
        int nl = dd[j] & 127;
        int r  = atomicAdd(&cur[b], 1);  // LDS returning atomic: fast
        if (r < ECAP)
            region[b * ECAP + r] = (nl << 18) | ((t[j] ? 1 : 0) << 17) | ss[j];
    }
}

// ---- gather: per-bucket CSR build in LDS, then 8 waves x 16 nodes ----
__global__ __launch_bounds__(512) void k_g(const __bf16* __restrict__ featb,
                                           const int* __restrict__ region,
                                           const int* __restrict__ bucketCnt,
                                           __bf16* __restrict__ s1b,
                                           __bf16* __restrict__ s0b,
                                           int* __restrict__ cc) {
    __shared__ int ncnt[NPB];
    __shared__ int csr[NPB * CSTRD];  // stride 49: breaks 2-bank aliasing
    int b = blockIdx.x, tid = threadIdx.x;
    int cntE = min(bucketCnt[b], ECAP);
    if (tid < NPB) ncnt[tid] = 0;
    __syncthreads();
    const int* reg = region + b * ECAP;
    for (int i = tid; i < cntE; i += 512) {
        int rec = reg[i];
        int nl = rec >> 18;
        int r = atomicAdd(&ncnt[nl], 1);
        if (r < DCAP) csr[nl * CSTRD + r] = rec & 0x3ffff;  // type|src
    }
    __syncthreads();

    int lane = tid & 63, wave = tid >> 6;
    int L = lane & 15, q = lane >> 4;
    int nl = wave * 16 + L;        // 8 waves x 16 nodes = 128
    int n = b * NPB + nl;
    int cnt = (n < NN) ? min(ncnt[nl], DCAP) : 0;
    const int* eb = &csr[nl * CSTRD];

    float sA[16], s1[16];
#pragma unroll
    for (int j = 0; j < 16; j++) { sA[j] = 0.f; s1[j] = 0.f; }
    int c1 = 0;
    int i = 0;
    for (; i + 2 <= cnt; i += 2) {  // unroll x2: 2x MLP on the latency chain
        int ea = eb[i], ebn = eb[i + 1];
        const __bf16* rowa = featb + (long)(ea & 0x1ffff) * 64;
        const __bf16* rowb = featb + (long)(ebn & 0x1ffff) * 64;
        bf16x8 a0 = *(const bf16x8*)(rowa + q * 8);
        bf16x8 a1 = *(const bf16x8*)(rowa + 32 + q * 8);
        bf16x8 b0v = *(const bf16x8*)(rowb + q * 8);
        bf16x8 b1v = *(const bf16x8*)(rowb + 32 + q * 8);
        int ta = (ea >> 17) & 1, tb = (ebn >> 17) & 1;
        c1 += ta + tb;
        float fa = (float)ta, fb = (float)tb;
#pragma unroll
        for (int j = 0; j < 8; j++) {
            float va = (float)a0[j], wa = (float)a1[j];
            float vb = (float)b0v[j], wb2 = (float)b1v[j];
            sA[j]     += va + vb;
            sA[8 + j] += wa + wb2;
            s1[j]     += fa * va + fb * vb;
            s1[8 + j] += fa * wa + fb * wb2;
        }
    }
    if (i < cnt) {
        int ea = eb[i];
        const __bf16* rowa = featb + (long)(ea & 0x1ffff) * 64;
        bf16x8 a0 = *(const bf16x8*)(rowa + q * 8);
        bf16x8 a1 = *(const bf16x8*)(rowa + 32 + q * 8);
        int ta = (ea >> 17) & 1;
        c1 += ta;
        float fa = (float)ta;
#pragma unroll
        for (int j = 0; j < 8; j++) {
            float va = (float)a0[j], wa = (float)a1[j];
            sA[j] += va;          sA[8 + j] += wa;
            s1[j] += fa * va;     s1[8 + j] += fa * wa;
        }
    }
    if (n >= NN) return;
    union { bf16x8 v; __bf16 e[8]; } u;
#pragma unroll
    for (int ch = 0; ch < 2; ch++) {
#pragma unroll
        for (int j = 0; j < 8; j++) u.e[j] = (__bf16)s1[ch * 8 + j];
        *(bf16x8*)(s1b + (long)n * 64 + ch * 32 + q * 8) = u.v;
#pragma unroll
        for (int j = 0; j < 8; j++) u.e[j] = (__bf16)(sA[ch * 8 + j] - s1[ch * 8 + j]);
        *(bf16x8*)(s0b + (long)n * 64 + ch * 32 + q * 8) = u.v;
    }
    if (q == 0) cc[n] = cnt | (c1 << 16);
}

// ---- MFMA stage: agg = S1@W0^T + S0@W1^T + count-biases; GRU; classifier ----
// R10: wih+whh LDS-staged (swizzled); w0/w1/wout global (L2-resident);
// unified bf16 transpose buffer -> 69632B LDS -> 2 blocks/CU.
__global__ __launch_bounds__(512, 4) void k_mm(const __bf16* __restrict__ s1b,
                                               const __bf16* __restrict__ s0b,
                                               const __bf16* __restrict__ featb,
                                               const float* __restrict__ feat,
                                               const int* __restrict__ cc,
                                               const __bf16* __restrict__ wb,
                                               const float* __restrict__ b0,
                                               const float* __restrict__ b1,
                                               const float* __restrict__ bih,
                                               const float* __restrict__ bhh,
                                               const float* __restrict__ bout,
                                               float* __restrict__ out) {
    // wlds: wih(0..12287) + whh(12288..24575), XOR-swizzled 16B blocks.
    // sH: per-wave bf16 [16][80]; holds agg-transpose first (dead before the
    // GRU h-write: same-wave in-order LDS), then h for the classifier.
    __shared__ __align__(16) __bf16 wlds[NWL];
    __shared__ __align__(16) __bf16 sHall[8][16 * 80];
    int tid = threadIdx.x, lane = tid & 63, wave = tid >> 6;
    int L = lane & 15, q = lane >> 4;
    int n0 = blockIdx.x * NPB + wave * 16;

    // per-wave global loads issued first: complete under the staging phase
    bf16x8 AS1[2], AS0[2], Aft[2];
    float fvv[4][4], fc1[4], fc0[4];
    if (n0 < NN) {
        const __bf16* r1 = s1b + (long)(n0 + L) * 64;
        const __bf16* r0 = s0b + (long)(n0 + L) * 64;
        const __bf16* fr = featb + (long)(n0 + L) * 64;
        AS1[0] = *(const bf16x8*)(r1 + q * 8);  AS1[1] = *(const bf16x8*)(r1 + 32 + q * 8);
        AS0[0] = *(const bf16x8*)(r0 + q * 8);  AS0[1] = *(const bf16x8*)(r0 + 32 + q * 8);
        Aft[0] = *(const bf16x8*)(fr + q * 8);  Aft[1] = *(const bf16x8*)(fr + 32 + q * 8);
#pragma unroll
        for (int nb = 0; nb < 4; nb++)
#pragma unroll
            for (int r = 0; r < 4; r++)
                fvv[nb][r] = feat[(long)(n0 + q * 4 + r) * 64 + nb * 16 + L];
        i32x4 cv = *(const i32x4*)(cc + n0 + q * 4);
#pragma unroll
        for (int r = 0; r < 4; r++) {
            int c1 = cv[r] >> 16, ct = cv[r] & 0xffff;
            fc1[r] = (float)c1; fc0[r] = (float)(ct - c1);
        }
    }

    // cooperative GRU-weight staging: 24576 bf16, swizzled 16B blocks
    const __bf16* wsrc = wb + 8192;  // wih | whh
    for (int k = tid * 8; k < NWL; k += 512 * 8) {
        bf16x8 v = *(const bf16x8*)(wsrc + k);
        int bo = k * 2;
        int so = bo ^ (((bo >> 7) & 7) << 4);
        *(bf16x8*)((char*)wlds + so) = v;
    }
    __syncthreads();
    if (n0 >= NN) return;

    __bf16* sH = sHall[wave];
    const __bf16* w0b = wb, * w1b = wb + 4096, * woutb = wb + 32768;
    f32x4 zz = {0.f, 0.f, 0.f, 0.f};

    // agg = S1@W0^T + S0@W1^T + per-count biases (B frags global, L2-hit)
#pragma unroll
    for (int nb = 0; nb < 4; nb++) {
        f32x4 acc = zz;
#pragma unroll
        for (int ch = 0; ch < 2; ch++) {
            int off = (nb * 16 + L) * 64 + ch * 32 + q * 8;
            acc = MFMA16(AS1[ch], *(const bf16x8*)(w0b + off), acc, 0, 0, 0);
            acc = MFMA16(AS0[ch], *(const bf16x8*)(w1b + off), acc, 0, 0, 0);
        }
        float bs0 = b0[nb * 16 + L], bs1 = b1[nb * 16 + L];
#pragma unroll
        for (int r = 0; r < 4; r++)
            sH[(q * 4 + r) * 80 + nb * 16 + L] =
                (__bf16)(acc[r] + fc1[r] * bs0 + fc0[r] * bs1);
    }

    // D->A transpose read (agg region of sH dead after this)
    bf16x8 Aag[2];
#pragma unroll
    for (int ch = 0; ch < 2; ch++)
        Aag[ch] = *(const bf16x8*)&sH[L * 80 + ch * 32 + q * 8];

    // GRU gates [r,z,n]; B fragments from LDS (wih @0, whh @12288)
#pragma unroll
    for (int nb = 0; nb < 4; nb++) {
        int row = nb * 16 + L;
        f32x4 aR = zz, aZ = zz, aIN = zz, aHN = zz;
#pragma unroll
        for (int ch = 0; ch < 2; ch++) {
            int ko = ch * 32 + q * 8;
            aR  = MFMA16(Aag[ch], ldw(wlds, row * 64 + ko), aR, 0, 0, 0);
            aR  = MFMA16(Aft[ch], ldw(wlds, 12288 + row * 64 + ko), aR, 0, 0, 0);
            aZ  = MFMA16(Aag[ch], ldw(wlds, (64 + row) * 64 + ko), aZ, 0, 0, 0);
            aZ  = MFMA16(Aft[ch], ldw(wlds, 12288 + (64 + row) * 64 + ko), aZ, 0, 0, 0);
            aIN = MFMA16(Aag[ch], ldw(wlds, (128 + row) * 64 + ko), aIN, 0, 0, 0);
            aHN = MFMA16(Aft[ch], ldw(wlds, 12288 + (128 + row) * 64 + ko), aHN, 0, 0, 0);
        }
        int h = row;
        float br  = bih[h] + bhh[h];
        float bz  = bih[64 + h] + bhh[64 + h];
        float bin = bih[128 + h];
        float bhn = bhh[128 + h];
#pragma unroll
        for (int r = 0; r < 4; r++) {
            float rv = sigmoidf_(aR[r] + br);
            float zv = sigmoidf_(aZ[r] + bz);
            float nv = tanhf(aIN[r] + bin + rv * (aHN[r] + bhn));
            float fv = fvv[nb][r];  // fp32 blend for accuracy
            sH[(q * 4 + r) * 80 + h] = (__bf16)((1.0f - zv) * nv + zv * fv);
        }
    }

    // out = h @ W_out^T + b_out (wout global, L2-hit)
    bf16x8 Ah0 = *(const bf16x8*)&sH[L * 80 + q * 8];
    bf16x8 Ah1 = *(const bf16x8*)&sH[L * 80 + 32 + q * 8];
    bf16x8 Bo0 = *(const bf16x8*)(woutb + L * 64 + q * 8);
    bf16x8 Bo1 = *(const bf16x8*)(woutb + L * 64 + 32 + q * 8);
    f32x4 o = zz;
    o = MFMA16(Ah0, Bo0, o, 0, 0, 0);
    o = MFMA16(Ah1, Bo1, o, 0, 0, 0);
    float bo = bout[L];
#pragma unroll
    for (int r = 0; r < 4; r++)
        out[(long)(n0 + q * 4 + r) * 16 + L] = o[r] + bo;
}

extern "C" void kernel_launch(void* const* d_in, const int* in_sizes, int n_in,
                              void* d_out, int out_size, void* d_ws, size_t ws_size,
                              hipStream_t stream) {
    const float* features = (const float*)d_in[0];
    const int*   src      = (const int*)d_in[1];
    const int*   dst      = (const int*)d_in[2];
    const unsigned char* etype = (const unsigned char*)d_in[3];
    const float* W0   = (const float*)d_in[4];
    const float* b0   = (const float*)d_in[5];
    const float* W1   = (const float*)d_in[6];
    const float* b1   = (const float*)d_in[7];
    const float* Wih  = (const float*)d_in[8];
    const float* Whh  = (const float*)d_in[9];
    const float* bih  = (const float*)d_in[10];
    const float* bhh  = (const float*)d_in[11];
    const float* Wout = (const float*)d_in[12];
    const float* bout = (const float*)d_in[13];
    float* out = (float*)d_out;

    char* ws = (char*)d_ws;
    size_t off = 0;
    __bf16* featb     = (__bf16*)(ws + off); off += (size_t)NN * 64 * 2;     // 12.8 MB
    int*    region    = (int*)(ws + off);    off += (size_t)BB * ECAP * 4;   // 5.0 MB
    int*    hist      = (int*)(ws + off);    off += (size_t)NB * BB * 4;     // 766 KB
    int*    blockBase = (int*)(ws + off);    off += (size_t)NB * BB * 4;     // 766 KB
    int*    bucketCnt = (int*)(ws + off);    off += (size_t)BB * 4;
    int*    cc        = (int*)(ws + off);    off += (size_t)NN * 4;
    __bf16* s1b       = (__bf16*)(ws + off); off += (size_t)NN * 64 * 2;     // 12.8 MB
    __bf16* s0b       = (__bf16*)(ws + off); off += (size_t)NN * 64 * 2;     // 12.8 MB
    __bf16* wb        = (__bf16*)(ws + off); off += 33792 * 2;
    int*    flag      = (int*)(ws + off);

    // 6628 = 1 detect + 132 weights + 6250 feat + 245 histogram blocks
    k_init<<<6628, 256, 0, stream>>>(etype, features, dst, W0, W1, Wih, Whh,
                                     Wout, featb, wb, hist, flag);
    k_s2<<<(BB + 3) / 4, 256, 0, stream>>>(hist, blockBase, bucketCnt);
    k_s3<<<NB, 512, 0, stream>>>(src, dst, etype, flag, blockBase, region);
    k_g<<<BB, 512, 0, stream>>>(featb, region, bucketCnt, s1b, s0b, cc);
    // one bucket (128 nodes) per block; wih/whh LDS-resident, 2 blocks/CU
    k_mm<<<BB, 512, 0, stream>>>(s1b, s0b, featb, features, cc, wb,
                                 b0, b1, bih, bhh, bout, out);
}

// Round 5
// 184.647 us; speedup vs baseline: 1.1319x; 1.0033x over previous
//
#include <hip/hip_runtime.h>

// GGNN on MI355X. N=100000, E=1000000, H=M=64, C=16.
// R6: deterministic bucket sort (hist / scan / place / gather / MFMA GRU).
// R9: weights->LDS killed the per-wave 64KB weight stream (77->45us).
// R10: LDS diet (bf16 transpose buf, only wih/whh staged) -> 2 blocks/CU.
// R11: top-5 shows 2x 42.8us fillBufferAligned (256MiB workspace re-poison
//      at 78% HBM peak) = ~85us harness floor; optimizable budget is the
//      ~100us of our kernels. Fuse k_g+k_mm: k_g's s1/sA lane layout IS
//      k_mm's A-fragment layout (lane (L,q) holds node n0+L dims q*8..+7,
//      32+q*8..+7 in both) -> convert in registers, delete the s1b/s0b
//      51MB round-trip + cc + one launch. Per-wave sH overlays the wave's
//      own dead csr chunk (3136B >= 2560B) -> LDS 74.8KB, 2 blocks/CU.
//      All arithmetic bit-identical -> absmax must stay 0.0078125 exactly.
// ws: [featb | region 782*1600 | hist 245*782 | blockBase 245*782 |
//      bucketCnt 782 | wb | flag]

typedef __bf16 bf16x8 __attribute__((ext_vector_type(8)));
typedef float  f32x4  __attribute__((ext_vector_type(4)));
typedef int    i32x4  __attribute__((ext_vector_type(4)));

#define MFMA16 __builtin_amdgcn_mfma_f32_16x16x32_bf16
#define NN   100000
#define EE   1000000
#define BB   782     // buckets (dst >> 7)
#define NPB  128     // nodes per bucket
#define ECAP 1600    // bucket region capacity (mean 1280, +9 sigma)
#define DCAP 48      // per-node degree cap (Poisson(10), P(>=48) ~ 1e-17)
#define CSTRD 49     // CSR LDS stride (conflict pad)
#define NB   245     // histogram blocks (4096 edges each)
#define NWL  24576   // LDS-staged weights: wih (12288) + whh (12288)

__device__ __forceinline__ float sigmoidf_(float x) {
    return 1.0f / (1.0f + __expf(-x));
}

// swizzled LDS weight fragment read: e = element offset (16B-aligned).
// XOR of row bits into the 16B-slot bits: conflict-free for the 128B-row-
// stride fragment pattern (T2).
__device__ __forceinline__ bf16x8 ldw(const __bf16* w, int e) {
    int bo = e * 2;
    bo ^= ((bo >> 7) & 7) << 4;
    return *(const bf16x8*)((const char*)w + bo);
}

// ---- fused init: dtype detect / weight cvt / feature cvt / dst histogram ----
__global__ __launch_bounds__(256) void k_init(const unsigned char* __restrict__ et,
                                              const float* __restrict__ feat,
                                              const int* __restrict__ dst,
                                              const float* __restrict__ w0,
                                              const float* __restrict__ w1,
                                              const float* __restrict__ wih,
                                              const float* __restrict__ whh,
                                              const float* __restrict__ wout,
                                              __bf16* __restrict__ featb,
                                              __bf16* __restrict__ wb,
                                              int* __restrict__ hist,
                                              int* __restrict__ flag) {
    int b = blockIdx.x, tid = threadIdx.x;
    if (b == 0) {
        // flag=1 iff any nonzero byte at offset%4!=0 in first 64KB (bool
        // storage); int32 0/1 storage has bytes 1..3 of every word zero.
        __shared__ int sdet[4];
        const i32x4* p = (const i32x4*)et + tid * 16;  // 256 B per thread
        unsigned acc = 0;
#pragma unroll
        for (int j = 0; j < 16; j++) {
            i32x4 w = p[j];
            acc |= (unsigned)(w[0] | w[1] | w[2] | w[3]) & 0xffffff00u;
        }
        unsigned long long m = __ballot(acc != 0);
        if ((tid & 63) == 0) sdet[tid >> 6] = (m != 0ULL);
        __syncthreads();
        if (tid == 0) *flag = sdet[0] | sdet[1] | sdet[2] | sdet[3];
        return;
    }
    if (b < 133) {  // 132 blocks * 256 = 33792 weights exactly
        int i = (b - 1) * 256 + tid;
        float v;
        if      (i < 4096)  v = w0[i];
        else if (i < 8192)  v = w1[i - 4096];
        else if (i < 20480) v = wih[i - 8192];
        else if (i < 32768) v = whh[i - 20480];
        else                v = wout[i - 32768];
        wb[i] = (__bf16)v;
        return;
    }
    if (b >= 6383) {  // fused k_s1: per-block dst-bucket histogram
        __shared__ int cnt[BB];
        int hb = b - 6383;
        for (int i = tid; i < BB; i += 256) cnt[i] = 0;
        __syncthreads();
        long e0 = (long)hb * 4096 + tid * 16;
#pragma unroll
        for (int g = 0; g < 2; g++) {
            long e = e0 + g * 8;
            if (e < EE) {
                i32x4 d0 = *(const i32x4*)(dst + e);
                i32x4 d1 = *(const i32x4*)(dst + e + 4);
#pragma unroll
                for (int j = 0; j < 4; j++) atomicAdd(&cnt[d0[j] >> 7], 1);
#pragma unroll
                for (int j = 0; j < 4; j++) atomicAdd(&cnt[d1[j] >> 7], 1);
            }
        }
        __syncthreads();
        for (int i = tid; i < BB; i += 256) hist[hb * BB + i] = cnt[i];
        return;
    }
    long i = ((long)(b - 133) * 256 + tid) * 4;
    if (i >= (long)NN * 64) return;
    f32x4 v = *(const f32x4*)(feat + i);
    union { __bf16 e[4]; unsigned long long u; } o;
#pragma unroll
    for (int j = 0; j < 4; j++) o.e[j] = (__bf16)v[j];
    *(unsigned long long*)(featb + i) = o.u;
}

// ---- s2: exclusive scan over blocks per bucket (1 wave/bucket) ----
__global__ __launch_bounds__(256) void k_s2(const int* __restrict__ hist,
                                            int* __restrict__ blockBase,
                                            int* __restrict__ bucketCnt) {
    int b = blockIdx.x * 4 + (threadIdx.x >> 6);
    int lane = threadIdx.x & 63;
    if (b >= BB) return;
    int carry = 0;
    for (int c = 0; c < 4; c++) {       // ceil(245/64) = 4 chunks
        int blk = c * 64 + lane;
        int v = (blk < NB) ? hist[blk * BB + b] : 0;
        int x = v;
#pragma unroll
        for (int off = 1; off < 64; off <<= 1) {
            int y = __shfl_up(x, off, 64);
            if (lane >= off) x += y;
        }
        if (blk < NB) blockBase[blk * BB + b] = x - v + carry;
        carry += __shfl(x, 63, 64);
    }
    if (lane == 0) bucketCnt[b] = carry;
}

// ---- s3: place edges deterministically (LDS cursors seeded w/ blockBase) ----
__global__ __launch_bounds__(512) void k_s3(const int* __restrict__ src,
                                            const int* __restrict__ dst,
                                            const unsigned char* __restrict__ etype,
                                            const int* __restrict__ flag,
                                            const int* __restrict__ blockBase,
                                            int* __restrict__ region) {
    __shared__ int cur[BB];
    int blk = blockIdx.x, tid = threadIdx.x;
    for (int i = tid; i < BB; i += 512) cur[i] = blockBase[blk * BB + i];
    __syncthreads();
    long e0 = (long)blk * 4096 + tid * 8;
    if (e0 >= EE) return;
    i32x4 s0 = *(const i32x4*)(src + e0);
    i32x4 s1 = *(const i32x4*)(src + e0 + 4);
    i32x4 d0 = *(const i32x4*)(dst + e0);
    i32x4 d1 = *(const i32x4*)(dst + e0 + 4);
    int t[8];
    if (*flag) {  // 1-byte bool storage
        unsigned long long w = *(const unsigned long long*)(etype + e0);
#pragma unroll
        for (int j = 0; j < 8; j++) t[j] = (int)((w >> (8 * j)) & 0xff);
    } else {      // int32 storage
        i32x4 w0 = *(const i32x4*)((const int*)etype + e0);
        i32x4 w1 = *(const i32x4*)((const int*)etype + e0 + 4);
#pragma unroll
        for (int j = 0; j < 4; j++) { t[j] = w0[j]; t[4 + j] = w1[j]; }
    }
    int dd[8] = {d0[0], d0[1], d0[2], d0[3], d1[0], d1[1], d1[2], d1[3]};
    int ss[8] = {s0[0], s0[1], s0[2], s0[3], s1[0], s1[1], s1[2], s1[3]};
#pragma unroll
    for (int j = 0; j < 8; j++) {
        int b  = dd[j] >> 7;
        int nl = dd[j] & 127;
        int r  = atomicAdd(&cur[b], 1);  // LDS returning atomic: fast
        if (r < ECAP)
            region[b * ECAP + r] = (nl << 18) | ((t[j] ? 1 : 0) << 17) | ss[j];
    }
}

// ---- fused gather + MFMA: CSR build -> per-node gather (A frags stay in
// registers) -> agg MFMA -> GRU -> classifier. One bucket (128 nodes)/block.
__global__ __launch_bounds__(512, 4) void k_gm(const __bf16* __restrict__ featb,
                                               const int* __restrict__ region,
                                               const int* __restrict__ bucketCnt,
                                               const float* __restrict__ feat,
                                               const __bf16* __restrict__ wb,
                                               const float* __restrict__ b0,
                                               const float* __restrict__ b1,
                                               const float* __restrict__ bih,
                                               const float* __restrict__ bhh,
                                               const float* __restrict__ bout,
                                               float* __restrict__ out) {
    // wlds: wih(0..12287)+whh(12288..24575), XOR-swizzled 16B blocks.
    // csr: per-node edge lists; wave w's 16-row chunk (3136B) is dead after
    // w's gather, then overlaid by w's sH (bf16 [16][80] = 2560B) — single-
    // wave in-order LDS makes this safe. Total 74.8KB -> 2 blocks/CU.
    __shared__ __align__(16) __bf16 wlds[NWL];
    __shared__ __align__(16) int csr[NPB * CSTRD];
    __shared__ int ncnt[NPB];
    int b = blockIdx.x, tid = threadIdx.x, lane = tid & 63, wave = tid >> 6;
    int L = lane & 15, q = lane >> 4;
    int n0 = b * NPB + wave * 16;   // NN%16==0: n0<NN => all 16 nodes valid

    // fire-and-forget loads: complete under CSR build + gather
    bf16x8 Aft[2];
    float fvv[4][4];
    if (n0 < NN) {
        const __bf16* fr = featb + (long)(n0 + L) * 64;
        Aft[0] = *(const bf16x8*)(fr + q * 8);
        Aft[1] = *(const bf16x8*)(fr + 32 + q * 8);
#pragma unroll
        for (int nb = 0; nb < 4; nb++)
#pragma unroll
            for (int r = 0; r < 4; r++)
                fvv[nb][r] = feat[(long)(n0 + q * 4 + r) * 64 + nb * 16 + L];
    }

    int cntE = min(bucketCnt[b], ECAP);
    if (tid < NPB) ncnt[tid] = 0;
    __syncthreads();
    // CSR build + weight staging (independent streams, latencies interleave)
    const int* reg = region + b * ECAP;
    for (int i = tid; i < cntE; i += 512) {
        int rec = reg[i];
        int nl = rec >> 18;
        int r = atomicAdd(&ncnt[nl], 1);
        if (r < DCAP) csr[nl * CSTRD + r] = rec & 0x3ffff;  // type|src
    }
    const __bf16* wsrc = wb + 8192;  // wih | whh
    for (int k = tid * 8; k < NWL; k += 512 * 8) {
        bf16x8 v = *(const bf16x8*)(wsrc + k);
        int bo = k * 2;
        int so = bo ^ (((bo >> 7) & 7) << 4);
        *(bf16x8*)((char*)wlds + so) = v;
    }
    __syncthreads();

    // ---- gather: 8 waves x 16 nodes; lane (L,q) owns node n0+L dims
    // {q*8..q*8+7, 32+q*8..+7} — exactly the MFMA A-fragment layout ----
    int nl = wave * 16 + L;
    int cnt = (n0 < NN) ? min(ncnt[nl], DCAP) : 0;
    const int* eb = &csr[nl * CSTRD];

    float sA[16], s1[16];
#pragma unroll
    for (int j = 0; j < 16; j++) { sA[j] = 0.f; s1[j] = 0.f; }
    int c1 = 0;
    int i = 0;
    for (; i + 2 <= cnt; i += 2) {  // unroll x2: 2x MLP on the latency chain
        int ea = eb[i], ebn = eb[i + 1];
        const __bf16* rowa = featb + (long)(ea & 0x1ffff) * 64;
        const __bf16* rowb = featb + (long)(ebn & 0x1ffff) * 64;
        bf16x8 a0 = *(const bf16x8*)(rowa + q * 8);
        bf16x8 a1 = *(const bf16x8*)(rowa + 32 + q * 8);
        bf16x8 b0v = *(const bf16x8*)(rowb + q * 8);
        bf16x8 b1v = *(const bf16x8*)(rowb + 32 + q * 8);
        int ta = (ea >> 17) & 1, tb = (ebn >> 17) & 1;
        c1 += ta + tb;
        float fa = (float)ta, fb = (float)tb;
#pragma unroll
        for (int j = 0; j < 8; j++) {
            float va = (float)a0[j], wa = (float)a1[j];
            float vb = (float)b0v[j], wb2 = (float)b1v[j];
            sA[j]     += va + vb;
            sA[8 + j] += wa + wb2;
            s1[j]     += fa * va + fb * vb;
            s1[8 + j] += fa * wa + fb * wb2;
        }
    }
    if (i < cnt) {
        int ea = eb[i];
        const __bf16* rowa = featb + (long)(ea & 0x1ffff) * 64;
        bf16x8 a0 = *(const bf16x8*)(rowa + q * 8);
        bf16x8 a1 = *(const bf16x8*)(rowa + 32 + q * 8);
        int ta = (ea >> 17) & 1;
        c1 += ta;
        float fa = (float)ta;
#pragma unroll
        for (int j = 0; j < 8; j++) {
            float va = (float)a0[j], wa = (float)a1[j];
            sA[j] += va;          sA[8 + j] += wa;
            s1[j] += fa * va;     s1[8 + j] += fa * wa;
        }
    }
    if (n0 >= NN) return;   // after last barrier: safe

    // ---- in-register A-fragment conversion (bit-identical to the old
    // s1b/s0b bf16 store + reload) ----
    bf16x8 AS1[2], AS0[2];
    {
        union { bf16x8 v; __bf16 e[8]; } u;
#pragma unroll
        for (int ch = 0; ch < 2; ch++) {
#pragma unroll
            for (int j = 0; j < 8; j++) u.e[j] = (__bf16)s1[ch * 8 + j];
            AS1[ch] = u.v;
#pragma unroll
            for (int j = 0; j < 8; j++) u.e[j] = (__bf16)(sA[ch * 8 + j] - s1[ch * 8 + j]);
            AS0[ch] = u.v;
        }
    }
    // counts exchange: every lane holds (cnt,c1) of node L; need node q*4+r
    int ccp = cnt | (c1 << 16);
    float fc1[4], fc0[4];
#pragma unroll
    for (int r = 0; r < 4; r++) {
        int v = __shfl(ccp, q * 4 + r, 64);
        int c1v = v >> 16;
        fc1[r] = (float)c1v; fc0[r] = (float)((v & 0xffff) - c1v);
    }

    // per-wave sH overlays this wave's own (dead) csr chunk
    __bf16* sH = (__bf16*)((char*)csr + wave * (16 * CSTRD * 4));
    const __bf16* w0b = wb, * w1b = wb + 4096, * woutb = wb + 32768;
    f32x4 zz = {0.f, 0.f, 0.f, 0.f};

    // agg = S1@W0^T + S0@W1^T + per-count biases (B frags global, L2-hit)
#pragma unroll
    for (int nb = 0; nb < 4; nb++) {
        f32x4 acc = zz;
#pragma unroll
        for (int ch = 0; ch < 2; ch++) {
            int off = (nb * 16 + L) * 64 + ch * 32 + q * 8;
            acc = MFMA16(AS1[ch], *(const bf16x8*)(w0b + off), acc, 0, 0, 0);
            acc = MFMA16(AS0[ch], *(const bf16x8*)(w1b + off), acc, 0, 0, 0);
        }
        float bs0 = b0[nb * 16 + L], bs1 = b1[nb * 16 + L];
#pragma unroll
        for (int r = 0; r < 4; r++)
            sH[(q * 4 + r) * 80 + nb * 16 + L] =
                (__bf16)(acc[r] + fc1[r] * bs0 + fc0[r] * bs1);
    }

    // D->A transpose read (agg region of sH dead after this)
    bf16x8 Aag[2];
#pragma unroll
    for (int ch = 0; ch < 2; ch++)
        Aag[ch] = *(const bf16x8*)&sH[L * 80 + ch * 32 + q * 8];

    // GRU gates [r,z,n]; B fragments from LDS (wih @0, whh @12288)
#pragma unroll
    for (int nb = 0; nb < 4; nb++) {
        int row = nb * 16 + L;
        f32x4 aR = zz, aZ = zz, aIN = zz, aHN = zz;
#pragma unroll
        for (int ch = 0; ch < 2; ch++) {
            int ko = ch * 32 + q * 8;
            aR  = MFMA16(Aag[ch], ldw(wlds, row * 64 + ko), aR, 0, 0, 0);
            aR  = MFMA16(Aft[ch], ldw(wlds, 12288 + row * 64 + ko), aR, 0, 0, 0);
            aZ  = MFMA16(Aag[ch], ldw(wlds, (64 + row) * 64 + ko), aZ, 0, 0, 0);
            aZ  = MFMA16(Aft[ch], ldw(wlds, 12288 + (64 + row) * 64 + ko), aZ, 0, 0, 0);
            aIN = MFMA16(Aag[ch], ldw(wlds, (128 + row) * 64 + ko), aIN, 0, 0, 0);
            aHN = MFMA16(Aft[ch], ldw(wlds, 12288 + (128 + row) * 64 + ko), aHN, 0, 0, 0);
        }
        int h = row;
        float br  = bih[h] + bhh[h];
        float bz  = bih[64 + h] + bhh[64 + h];
        float bin = bih[128 + h];
        float bhn = bhh[128 + h];
#pragma unroll
        for (int r = 0; r < 4; r++) {
            float rv = sigmoidf_(aR[r] + br);
            float zv = sigmoidf_(aZ[r] + bz);
            float nv = tanhf(aIN[r] + bin + rv * (aHN[r] + bhn));
            float fv = fvv[nb][r];  // fp32 blend for accuracy
            sH[(q * 4 + r) * 80 + h] = (__bf16)((1.0f - zv) * nv + zv * fv);
        }
    }

    // out = h @ W_out^T + b_out (wout global, L2-hit)
    bf16x8 Ah0 = *(const bf16x8*)&sH[L * 80 + q * 8];
    bf16x8 Ah1 = *(const bf16x8*)&sH[L * 80 + 32 + q * 8];
    bf16x8 Bo0 = *(const bf16x8*)(woutb + L * 64 + q * 8);
    bf16x8 Bo1 = *(const bf16x8*)(woutb + L * 64 + 32 + q * 8);
    f32x4 o = zz;
    o = MFMA16(Ah0, Bo0, o, 0, 0, 0);
    o = MFMA16(Ah1, Bo1, o, 0, 0, 0);
    float bo = bout[L];
#pragma unroll
    for (int r = 0; r < 4; r++)
        out[(long)(n0 + q * 4 + r) * 16 + L] = o[r] + bo;
}

extern "C" void kernel_launch(void* const* d_in, const int* in_sizes, int n_in,
                              void* d_out, int out_size, void* d_ws, size_t ws_size,
                              hipStream_t stream) {
    const float* features = (const float*)d_in[0];
    const int*   src      = (const int*)d_in[1];
    const int*   dst      = (const int*)d_in[2];
    const unsigned char* etype = (const unsigned char*)d_in[3];
    const float* W0   = (const float*)d_in[4];
    const float* b0   = (const float*)d_in[5];
    const float* W1   = (const float*)d_in[6];
    const float* b1   = (const float*)d_in[7];
    const float* Wih  = (const float*)d_in[8];
    const float* Whh  = (const float*)d_in[9];
    const float* bih  = (const float*)d_in[10];
    const float* bhh  = (const float*)d_in[11];
    const float* Wout = (const float*)d_in[12];
    const float* bout = (const float*)d_in[13];
    float* out = (float*)d_out;

    char* ws = (char*)d_ws;
    size_t off = 0;
    __bf16* featb     = (__bf16*)(ws + off); off += (size_t)NN * 64 * 2;     // 12.8 MB
    int*    region    = (int*)(ws + off);    off += (size_t)BB * ECAP * 4;   // 5.0 MB
    int*    hist      = (int*)(ws + off);    off += (size_t)NB * BB * 4;     // 766 KB
    int*    blockBase = (int*)(ws + off);    off += (size_t)NB * BB * 4;     // 766 KB
    int*    bucketCnt = (int*)(ws + off);    off += (size_t)BB * 4;
    __bf16* wb        = (__bf16*)(ws + off); off += 33792 * 2;
    int*    flag      = (int*)(ws + off);

    // 6628 = 1 detect + 132 weights + 6250 feat + 245 histogram blocks
    k_init<<<6628, 256, 0, stream>>>(etype, features, dst, W0, W1, Wih, Whh,
                                     Wout, featb, wb, hist, flag);
    k_s2<<<(BB + 3) / 4, 256, 0, stream>>>(hist, blockBase, bucketCnt);
    k_s3<<<NB, 512, 0, stream>>>(src, dst, etype, flag, blockBase, region);
    // fused gather + MFMA: one bucket (128 nodes) per block
    k_gm<<<BB, 512, 0, stream>>>(featb, region, bucketCnt, features, wb,
                                 b0, b1, bih, bhh, bout, out);
}